// Round 4
// baseline (481.502 us; speedup 1.0000x reference)
//
#include <hip/hip_runtime.h>

typedef __attribute__((ext_vector_type(8))) short short8;
typedef __attribute__((ext_vector_type(4))) float f32x4;
typedef __attribute__((ext_vector_type(16))) float f32x16;
typedef __attribute__((ext_vector_type(4))) unsigned short us4;

#define NTOK 343
#define BMP 352      // bias/mask padded row pitch (elements)
#define VTP 352      // v_t padded row pitch (elements)
#define LOG2E 1.4426950408889634f

// ---- workspace layout (bytes) ----
#define OFF_QG   0u
#define OFF_KG   33718272u     // 256*6*343*32*2
#define OFF_VT   67436544u
#define OFF_AO   102039552u    // x1b during precompute/proj; a_o afterwards
#define OFF_WB   135757824u    // bf16 weights: wq | wkv | wp
// bias_bf/mask_bf live in spare d_out space

__device__ __forceinline__ unsigned short f2bf(float f) {
  union { float f; unsigned u; } v; v.f = f;
  unsigned r = v.u + 0x7FFFu + ((v.u >> 16) & 1u);
  return (unsigned short)(r >> 16);
}

__device__ __forceinline__ float bf2f(unsigned short b) {
  union { unsigned u; float f; } v; v.u = ((unsigned)b) << 16;
  return v.f;
}

__device__ __forceinline__ short8 ld8(const unsigned short* p) {
  return *reinterpret_cast<const short8*>(p);
}

__device__ __forceinline__ float fexp2(float x) {
  float r; asm("v_exp_f32 %0, %1" : "=v"(r) : "v"(x)); return r;
}

__device__ __forceinline__ unsigned cvtpk(float a, float b) {
  unsigned r; asm("v_cvt_pk_bf16_f32 %0, %1, %2" : "=v"(r) : "v"(a), "v"(b)); return r;
}

__device__ __forceinline__ f32x16 mfma32(short8 a, short8 b, f32x16 c) {
  return __builtin_amdgcn_mfma_f32_32x32x16_bf16(a, b, c, 0, 0, 0);
}

union frag_u { unsigned u[4]; short8 s8; };

// ---------------- kernel B: precompute ----------------
__global__ __launch_bounds__(256) void precompute(
    const float* __restrict__ x1, const float* __restrict__ x2,
    const float* __restrict__ mask, const float* __restrict__ table,
    const int* __restrict__ rel_idx,
    const float* __restrict__ qw, const float* __restrict__ kvw, const float* __restrict__ pw,
    unsigned short* __restrict__ x1b, unsigned short* __restrict__ x2b,
    unsigned short* __restrict__ wq_bf, unsigned short* __restrict__ wkv_bf,
    unsigned short* __restrict__ wp_bf,
    unsigned short* __restrict__ bias_bf, unsigned short* __restrict__ mask_bf,
    unsigned short* __restrict__ v_t)
{
  const int idx = blockIdx.x * 256 + threadIdx.x;
  if (idx < 8429568) {
    const float* src; unsigned short* dst; int i;
    if (idx < 4214784) { src = x1; dst = x1b; i = idx; }
    else               { src = x2; dst = x2b; i = idx - 4214784; }
    f32x4 v = *reinterpret_cast<const f32x4*>(src + i * 4);
    us4 o; o[0] = f2bf(v[0]); o[1] = f2bf(v[1]); o[2] = f2bf(v[2]); o[3] = f2bf(v[3]);
    *reinterpret_cast<us4*>(dst + i * 4) = o;
  } else if (idx < 8466432) {
    const int wi = idx - 8429568;
    const float* src; unsigned short* dst; int i;
    if (wi < 9216)       { src = qw;  dst = wq_bf;  i = wi; }
    else if (wi < 27648) { src = kvw; dst = wkv_bf; i = wi - 9216; }
    else                 { src = pw;  dst = wp_bf;  i = wi - 27648; }
    f32x4 v = *reinterpret_cast<const f32x4*>(src + i * 4);
    us4 o; o[0] = f2bf(v[0]); o[1] = f2bf(v[1]); o[2] = f2bf(v[2]); o[3] = f2bf(v[3]);
    *reinterpret_cast<us4*>(dst + i * 4) = o;
  } else if (idx < 10398208) {
    const int mi = idx - 8466432;
    const int row = mi / 88, q = mi - row * 88;
    const int j0 = q * 4;
    unsigned short* dst = mask_bf + row * BMP + j0;
    if (q < 85) {
      const float* src = mask + row * NTOK + j0;
      us4 o; o[0] = f2bf(LOG2E * src[0]); o[1] = f2bf(LOG2E * src[1]);
      o[2] = f2bf(LOG2E * src[2]); o[3] = f2bf(LOG2E * src[3]);
      *reinterpret_cast<us4*>(dst) = o;
    } else {
      us4 o;
      #pragma unroll
      for (int i = 0; i < 4; ++i) {
        const int col = j0 + i;
        o[i] = (col < NTOK) ? f2bf(LOG2E * mask[row * NTOK + col]) : (unsigned short)0;
      }
      *reinterpret_cast<us4*>(dst) = o;
    }
  } else if (idx < 10515857) {
    const int i = idx - 10398208;
    const int ri = rel_idx[i] * 6;
    const int rrow = i / NTOK, j = i - rrow * NTOK;
    unsigned short* dst = bias_bf + rrow * BMP + j;
    #pragma unroll
    for (int h = 0; h < 6; ++h) dst[h * (NTOK * BMP)] = f2bf(LOG2E * table[ri + h]);
  } else if (idx < 10517915) {
    const int p = idx - 10515857;
    unsigned short* dst = bias_bf + p * BMP + NTOK;
    #pragma unroll
    for (int c = 0; c < 9; ++c) dst[c] = 0;
  } else if (idx < 10567067) {
    const int row = idx - 10517915;
    unsigned short* dst = v_t + row * VTP + NTOK;
    #pragma unroll
    for (int c = 0; c < 9; ++c) dst[c] = 0;
  }
}

// ---------------- kernel A: fused Q/K/V projection ----------------
__global__ __launch_bounds__(256) void proj(
    const unsigned short* __restrict__ x1b, const unsigned short* __restrict__ x2b,
    const unsigned short* __restrict__ wq_bf, const unsigned short* __restrict__ wkv_bf,
    const float* __restrict__ qb, const float* __restrict__ kvb,
    unsigned short* __restrict__ q_g, unsigned short* __restrict__ k_g,
    unsigned short* __restrict__ v_t)
{
  const int tid = threadIdx.x;
  const int wv = tid >> 6, lane = tid & 63, lg = lane >> 4, lr = lane & 15;
  const int path = blockIdx.y;
  const int row0 = blockIdx.x * 128 + wv * 32;

  const unsigned short* X = (path == 0) ? x1b : x2b;
  const unsigned short* W = (path == 0) ? wq_bf : (path == 1 ? wkv_bf : wkv_bf + 36864);
  const float* Bv = (path == 0) ? qb : (path == 1 ? kvb : kvb + 192);

  f32x4 acc[2][12];
  #pragma unroll
  for (int i = 0; i < 2; ++i)
    #pragma unroll
    for (int j = 0; j < 12; ++j) acc[i][j] = (f32x4){0.f, 0.f, 0.f, 0.f};

  const unsigned short* xr0 = X + (row0 + lr) * 192;
  const unsigned short* xr1 = xr0 + 16 * 192;
  const unsigned short* wr  = W + lr * 192;

  if (path < 2) {
    #pragma unroll
    for (int kk = 0; kk < 6; ++kk) {
      const int k0 = kk * 32 + lg * 8;
      const short8 a0 = ld8(xr0 + k0);
      const short8 a1 = ld8(xr1 + k0);
      #pragma unroll
      for (int ct = 0; ct < 12; ++ct) {
        const short8 wf = ld8(wr + ct * 3072 + k0);
        acc[0][ct] = __builtin_amdgcn_mfma_f32_16x16x32_bf16(a0, wf, acc[0][ct], 0, 0, 0);
        acc[1][ct] = __builtin_amdgcn_mfma_f32_16x16x32_bf16(a1, wf, acc[1][ct], 0, 0, 0);
      }
    }
    unsigned short* out = (path == 0) ? q_g : k_g;
    const float scale = (path == 0) ? (0.17677669529663687f * LOG2E) : 1.0f;
    float bs[12];
    #pragma unroll
    for (int ct = 0; ct < 12; ++ct) bs[ct] = Bv[ct * 16 + lr];
    #pragma unroll
    for (int rs = 0; rs < 2; ++rs) {
      const int t0 = row0 + rs * 16 + lg * 4;
      const int b0 = t0 / NTOK;
      const int n0 = t0 - b0 * NTOK;
      #pragma unroll
      for (int r = 0; r < 4; ++r) {
        int b = b0, n = n0 + r;
        if (n >= NTOK) { b++; n -= NTOK; }
        unsigned short* ob = out + (b * 6 * NTOK + n) * 32 + lr;
        #pragma unroll
        for (int ct = 0; ct < 12; ++ct) {
          const int h = ct >> 1, dhi = (ct & 1) * 16;
          ob[h * (NTOK * 32) + dhi] = f2bf((acc[rs][ct][r] + bs[ct]) * scale);
        }
      }
    }
  } else {
    #pragma unroll
    for (int kk = 0; kk < 6; ++kk) {
      const int k0 = kk * 32 + lg * 8;
      const short8 a0 = ld8(xr0 + k0);
      const short8 a1 = ld8(xr1 + k0);
      #pragma unroll
      for (int ct = 0; ct < 12; ++ct) {
        const short8 wf = ld8(wr + ct * 3072 + k0);
        acc[0][ct] = __builtin_amdgcn_mfma_f32_16x16x32_bf16(wf, a0, acc[0][ct], 0, 0, 0);
        acc[1][ct] = __builtin_amdgcn_mfma_f32_16x16x32_bf16(wf, a1, acc[1][ct], 0, 0, 0);
      }
    }
    f32x4 bv[12];
    #pragma unroll
    for (int ct = 0; ct < 12; ++ct)
      bv[ct] = *reinterpret_cast<const f32x4*>(Bv + ct * 16 + lg * 4);
    #pragma unroll
    for (int tt = 0; tt < 2; ++tt) {
      const int t = row0 + tt * 16 + lr;
      const int b = t / NTOK;
      const int n = t - b * NTOK;
      unsigned short* vb = v_t + b * (6 * 32 * VTP) + n;
      #pragma unroll
      for (int ct = 0; ct < 12; ++ct) {
        unsigned short* vc = vb + (ct * 16 + lg * 4) * VTP;
        #pragma unroll
        for (int r = 0; r < 4; ++r) {
          vc[r * VTP] = f2bf(acc[tt][ct][r] + bv[ct][r]);
        }
      }
    }
  }
}

// ---------------- kernel C: attention v4 (registers-only flash, 32x32 MFMA) ----------------
// S^T = K*Q^T (32x32x16 x2), online softmax lane-local (q = lane&31),
// P^T redistributed in-register (cvt_pk + shfl_xor(32)), O^T = V^T*P^T.
__global__ __launch_bounds__(256, 3) void attn(
    const unsigned short* __restrict__ q_g, const unsigned short* __restrict__ k_g,
    const unsigned short* __restrict__ v_t, const unsigned short* __restrict__ bias_bf,
    const unsigned short* __restrict__ mask_bf, unsigned short* __restrict__ attn_out)
{
  const int tid = threadIdx.x;
  const int wv = tid >> 6, lane = tid & 63;
  const int l31 = lane & 31, hi = lane >> 5;
  const int bid = blockIdx.x;
  const int b = bid / 6, h = bid - b * 6;
  const int w = b & 63;

  const unsigned short* qp = q_g + bid * (NTOK * 32);
  const unsigned short* kp = k_g + bid * (NTOK * 32);
  const unsigned short* vp = v_t + bid * (32 * VTP);
  const unsigned short* bias_h = bias_bf + h * (NTOK * BMP);
  const unsigned short* mask_w = mask_bf + w * (NTOK * BMP);
  const unsigned short* vrow = vp + l31 * VTP;

  for (int qt = wv; qt < 11; qt += 4) {
    const int qq = qt * 32 + l31;
    const int qrc = qq < NTOK ? qq : NTOK - 1;
    const short8 qf0 = ld8(qp + qrc * 32 + hi * 8);        // dd 0..15
    const short8 qf1 = ld8(qp + qrc * 32 + 16 + hi * 8);   // dd 16..31
    const unsigned short* bmb = bias_h + qrc * BMP;
    const unsigned short* bmm = mask_w + qrc * BMP;

    f32x16 O;
    #pragma unroll
    for (int r = 0; r < 16; ++r) O[r] = 0.f;
    float m = -3.0e38f, sum = 0.f;

    for (int kt = 0; kt < 11; ++kt) {
      const int kb = kt * 32;
      // --- S^T tile: D[k=crow(r,hi)][q=l31] ---
      const unsigned short* krow = kp + (kb + l31) * 32;
      const short8 kf0 = ld8(krow + hi * 8);
      const short8 kf1 = ld8(krow + 16 + hi * 8);
      f32x16 s;
      #pragma unroll
      for (int r = 0; r < 16; ++r) s[r] = 0.f;
      s = mfma32(kf0, qf0, s);
      s = mfma32(kf1, qf1, s);

      // --- bias + mask + tail, tile max ---
      float p[16];
      float tmax = -3.0e38f;
      #pragma unroll
      for (int g = 0; g < 4; ++g) {
        const int c0 = kb + g * 8 + hi * 4;
        const us4 b4 = *reinterpret_cast<const us4*>(bmb + c0);
        const us4 m4 = *reinterpret_cast<const us4*>(bmm + c0);
        #pragma unroll
        for (int j = 0; j < 4; ++j) {
          float v = s[g * 4 + j] + (bf2f(b4[j]) + bf2f(m4[j]));
          if (kt == 10 && (g * 8 + hi * 4 + j) >= 23) v = -3.0e38f;
          p[g * 4 + j] = v;
          tmax = fmaxf(tmax, v);
        }
      }
      tmax = fmaxf(tmax, __shfl_xor(tmax, 32));   // merge q-pair halves

      // --- online max with defer threshold (T13) ---
      if (!__all(tmax <= m + 8.f)) {
        const float newm = fmaxf(m, tmax);
        const float sc = fexp2(m - newm);
        m = newm;
        sum *= sc;
        #pragma unroll
        for (int r = 0; r < 16; ++r) O[r] *= sc;
      }

      // --- exp + sum (lane-local) ---
      #pragma unroll
      for (int r = 0; r < 16; ++r) p[r] = fexp2(p[r] - m);
      #pragma unroll
      for (int r = 0; r < 16; ++r) sum += p[r];

      // --- pack P^T and redistribute to B-fragments ---
      const unsigned c01 = cvtpk(p[0], p[1]),  c23 = cvtpk(p[2], p[3]);
      const unsigned c45 = cvtpk(p[4], p[5]),  c67 = cvtpk(p[6], p[7]);
      const unsigned d01 = cvtpk(p[8], p[9]),  d23 = cvtpk(p[10], p[11]);
      const unsigned d45 = cvtpk(p[12], p[13]), d67 = cvtpk(p[14], p[15]);
      const unsigned sc01 = __shfl_xor((int)c01, 32), sc23 = __shfl_xor((int)c23, 32);
      const unsigned sc45 = __shfl_xor((int)c45, 32), sc67 = __shfl_xor((int)c67, 32);
      const unsigned sd01 = __shfl_xor((int)d01, 32), sd23 = __shfl_xor((int)d23, 32);
      const unsigned sd45 = __shfl_xor((int)d45, 32), sd67 = __shfl_xor((int)d67, 32);
      frag_u P0, P1;
      P0.u[0] = hi ? sc45 : c01;  P0.u[1] = hi ? sc67 : c23;
      P0.u[2] = hi ? c45 : sc01;  P0.u[3] = hi ? c67 : sc23;
      P1.u[0] = hi ? sd45 : d01;  P1.u[1] = hi ? sd67 : d23;
      P1.u[2] = hi ? d45 : sd01;  P1.u[3] = hi ? d67 : sd23;

      // --- O^T += V^T * P^T ---
      const short8 vf0 = ld8(vrow + kb + hi * 8);        // k 0..15 of tile
      const short8 vf1 = ld8(vrow + kb + 16 + hi * 8);   // k 16..31
      O = mfma32(vf0, P0.s8, O);
      O = mfma32(vf1, P1.s8, O);
    }

    // --- normalize + store: O^T[d=crow(r,hi)][q=l31] ---
    const float sumT = sum + __shfl_xor(sum, 32);
    const float inv = 1.0f / sumT;
    if (qq < NTOK) {
      unsigned short* op = attn_out + (b * NTOK + qq) * 192 + h * 32;
      #pragma unroll
      for (int g = 0; g < 4; ++g) {
        us4 ov;
        #pragma unroll
        for (int j = 0; j < 4; ++j) ov[j] = f2bf(O[g * 4 + j] * inv);
        *reinterpret_cast<us4*>(op + g * 8 + hi * 4) = ov;
      }
    }
  }
}

// ---------------- kernel D: output projection ----------------
__global__ __launch_bounds__(256) void proj_out(
    const unsigned short* __restrict__ a_in, const unsigned short* __restrict__ wp_bf,
    const float* __restrict__ pb, float* __restrict__ out)
{
  const int tid = threadIdx.x;
  const int wv = tid >> 6, lane = tid & 63, lg = lane >> 4, lr = lane & 15;
  const int row0 = blockIdx.x * 128 + wv * 32;

  f32x4 acc[2][12];
  #pragma unroll
  for (int i = 0; i < 2; ++i)
    #pragma unroll
    for (int j = 0; j < 12; ++j) acc[i][j] = (f32x4){0.f, 0.f, 0.f, 0.f};

  const unsigned short* xr0 = a_in + (row0 + lr) * 192;
  const unsigned short* xr1 = xr0 + 16 * 192;
  const unsigned short* wr  = wp_bf + lr * 192;

  #pragma unroll
  for (int kk = 0; kk < 6; ++kk) {
    const int k0 = kk * 32 + lg * 8;
    const short8 a0 = ld8(xr0 + k0);
    const short8 a1 = ld8(xr1 + k0);
    #pragma unroll
    for (int ct = 0; ct < 12; ++ct) {
      const short8 wf = ld8(wr + ct * 3072 + k0);
      acc[0][ct] = __builtin_amdgcn_mfma_f32_16x16x32_bf16(a0, wf, acc[0][ct], 0, 0, 0);
      acc[1][ct] = __builtin_amdgcn_mfma_f32_16x16x32_bf16(a1, wf, acc[1][ct], 0, 0, 0);
    }
  }

  float bs[12];
  #pragma unroll
  for (int ct = 0; ct < 12; ++ct) bs[ct] = pb[ct * 16 + lr];
  #pragma unroll
  for (int rs = 0; rs < 2; ++rs) {
    #pragma unroll
    for (int r = 0; r < 4; ++r) {
      const int t = row0 + rs * 16 + lg * 4 + r;
      float* op = out + t * 192 + lr;
      #pragma unroll
      for (int ct = 0; ct < 12; ++ct)
        op[ct * 16] = acc[rs][ct][r] + bs[ct];
    }
  }
}

extern "C" void kernel_launch(void* const* d_in, const int* in_sizes, int n_in,
                              void* d_out, int out_size, void* d_ws, size_t ws_size,
                              hipStream_t stream) {
  const float* x1    = (const float*)d_in[0];
  const float* x2    = (const float*)d_in[1];
  const float* mask  = (const float*)d_in[2];
  const float* table = (const float*)d_in[3];
  const float* qw    = (const float*)d_in[4];
  const float* qb    = (const float*)d_in[5];
  const float* kvw   = (const float*)d_in[6];
  const float* kvb   = (const float*)d_in[7];
  const float* pw    = (const float*)d_in[8];
  const float* pb    = (const float*)d_in[9];
  const int* rel_idx = (const int*)d_in[10];

  char* ws = (char*)d_ws;
  char* outc = (char*)d_out;
  unsigned short* q_g     = (unsigned short*)(ws + OFF_QG);
  unsigned short* k_g     = (unsigned short*)(ws + OFF_KG);
  unsigned short* v_t     = (unsigned short*)(ws + OFF_VT);
  unsigned short* a_o     = (unsigned short*)(ws + OFF_AO);
  unsigned short* wq_bf   = (unsigned short*)(ws + OFF_WB);
  unsigned short* wkv_bf  = wq_bf + 36864;
  unsigned short* wp_bf   = wkv_bf + 73728;
  unsigned short* x1b     = a_o;                               // aliased (dead after proj)
  unsigned short* x2b     = (unsigned short*)outc;             // aliased (d_out written last)
  unsigned short* bias_bf = (unsigned short*)(outc + 33718272);
  unsigned short* mask_bf = (unsigned short*)(outc + 35167104);

  hipLaunchKernelGGL(precompute, dim3(41278), dim3(256), 0, stream,
                     x1, x2, mask, table, rel_idx, qw, kvw, pw,
                     x1b, x2b, wq_bf, wkv_bf, wp_bf, bias_bf, mask_bf, v_t);
  hipLaunchKernelGGL(proj, dim3(686, 3), dim3(256), 0, stream,
                     x1b, x2b, wq_bf, wkv_bf, qb, kvb, q_g, k_g, v_t);
  hipLaunchKernelGGL(attn, dim3(1536), dim3(256), 0, stream,
                     q_g, k_g, v_t, bias_bf, mask_bf, a_o);
  hipLaunchKernelGGL(proj_out, dim3(686), dim3(256), 0, stream,
                     a_o, wp_bf, pb, (float*)d_out);
}

// Round 5
// 338.121 us; speedup vs baseline: 1.4241x; 1.4241x over previous
//
#include <hip/hip_runtime.h>

typedef __attribute__((ext_vector_type(8))) short short8;
typedef __attribute__((ext_vector_type(4))) float f32x4;
typedef __attribute__((ext_vector_type(16))) float f32x16;
typedef __attribute__((ext_vector_type(4))) unsigned short us4;

#define NTOK 343
#define BMP 352      // bias/mask padded row pitch (elements)
#define LOG2E 1.4426950408889634f
#define FPLANE 11264 // shorts per (b,h) fragment plane: 11 tiles x 1024

// ---- workspace layout (bytes) ----
#define OFF_QG   0u            // q: [bh][tok][32]            33,718,272
#define OFF_KG   33718272u     // k frag planes: 1536*11264*2 34,603,008
#define OFF_VT   68321280u     // v frag planes               34,603,008
#define OFF_AO   102924288u    // x1b during pre/proj; a_o    33,718,272
#define OFF_WB   136642560u    // bf16 weights
// bias_bf/mask_bf live in spare d_out space

__device__ __forceinline__ unsigned short f2bf(float f) {
  union { float f; unsigned u; } v; v.f = f;
  unsigned r = v.u + 0x7FFFu + ((v.u >> 16) & 1u);
  return (unsigned short)(r >> 16);
}

__device__ __forceinline__ float bf2f(unsigned short b) {
  union { unsigned u; float f; } v; v.u = ((unsigned)b) << 16;
  return v.f;
}

__device__ __forceinline__ short8 ld8(const unsigned short* p) {
  return *reinterpret_cast<const short8*>(p);
}

__device__ __forceinline__ float fexp2(float x) {
  float r; asm("v_exp_f32 %0, %1" : "=v"(r) : "v"(x)); return r;
}

__device__ __forceinline__ unsigned cvtpk(float a, float b) {
  unsigned r; asm("v_cvt_pk_bf16_f32 %0, %1, %2" : "=v"(r) : "v"(a), "v"(b)); return r;
}

__device__ __forceinline__ f32x16 mfma32(short8 a, short8 b, f32x16 c) {
  return __builtin_amdgcn_mfma_f32_32x32x16_bf16(a, b, c, 0, 0, 0);
}

union frag_u { unsigned u[4]; short8 s8; };

// fragment-plane short index for K: element (tok, d) -> tile = tok>>5
//   idx = tile*1024 + ((d>>3 & 1)*32 + (tok&31))*8 + ((d>>4)&1)*512 + (d&7)
// fragment-plane short index for V^T: element (d, tok)
//   idx = tile*1024 + (((tok>>3)&1)*32 + d)*8 + ((tok>>4)&1)*512 + (tok&7)

// ---------------- kernel B: precompute ----------------
__global__ __launch_bounds__(256) void precompute(
    const float* __restrict__ x1, const float* __restrict__ x2,
    const float* __restrict__ mask, const float* __restrict__ table,
    const int* __restrict__ rel_idx,
    const float* __restrict__ qw, const float* __restrict__ kvw, const float* __restrict__ pw,
    unsigned short* __restrict__ x1b, unsigned short* __restrict__ x2b,
    unsigned short* __restrict__ wq_bf, unsigned short* __restrict__ wkv_bf,
    unsigned short* __restrict__ wp_bf,
    unsigned short* __restrict__ bias_bf, unsigned short* __restrict__ mask_bf,
    unsigned short* __restrict__ v_frag)
{
  const int idx = blockIdx.x * 256 + threadIdx.x;
  if (idx < 8429568) {
    const float* src; unsigned short* dst; int i;
    if (idx < 4214784) { src = x1; dst = x1b; i = idx; }
    else               { src = x2; dst = x2b; i = idx - 4214784; }
    f32x4 v = *reinterpret_cast<const f32x4*>(src + i * 4);
    us4 o; o[0] = f2bf(v[0]); o[1] = f2bf(v[1]); o[2] = f2bf(v[2]); o[3] = f2bf(v[3]);
    *reinterpret_cast<us4*>(dst + i * 4) = o;
  } else if (idx < 8466432) {
    const int wi = idx - 8429568;
    const float* src; unsigned short* dst; int i;
    if (wi < 9216)       { src = qw;  dst = wq_bf;  i = wi; }
    else if (wi < 27648) { src = kvw; dst = wkv_bf; i = wi - 9216; }
    else                 { src = pw;  dst = wp_bf;  i = wi - 27648; }
    f32x4 v = *reinterpret_cast<const f32x4*>(src + i * 4);
    us4 o; o[0] = f2bf(v[0]); o[1] = f2bf(v[1]); o[2] = f2bf(v[2]); o[3] = f2bf(v[3]);
    *reinterpret_cast<us4*>(dst + i * 4) = o;
  } else if (idx < 10398208) {
    const int mi = idx - 8466432;
    const int row = mi / 88, q = mi - row * 88;
    const int j0 = q * 4;
    unsigned short* dst = mask_bf + row * BMP + j0;
    if (q < 85) {
      const float* src = mask + row * NTOK + j0;
      us4 o; o[0] = f2bf(LOG2E * src[0]); o[1] = f2bf(LOG2E * src[1]);
      o[2] = f2bf(LOG2E * src[2]); o[3] = f2bf(LOG2E * src[3]);
      *reinterpret_cast<us4*>(dst) = o;
    } else {
      us4 o;
      #pragma unroll
      for (int i = 0; i < 4; ++i) {
        const int col = j0 + i;
        o[i] = (col < NTOK) ? f2bf(LOG2E * mask[row * NTOK + col]) : (unsigned short)0;
      }
      *reinterpret_cast<us4*>(dst) = o;
    }
  } else if (idx < 10515857) {
    const int i = idx - 10398208;
    const int ri = rel_idx[i] * 6;
    const int rrow = i / NTOK, j = i - rrow * NTOK;
    unsigned short* dst = bias_bf + rrow * BMP + j;
    #pragma unroll
    for (int h = 0; h < 6; ++h) dst[h * (NTOK * BMP)] = f2bf(LOG2E * table[ri + h]);
  } else if (idx < 10517915) {
    const int p = idx - 10515857;
    unsigned short* dst = bias_bf + p * BMP + NTOK;
    #pragma unroll
    for (int c = 0; c < 9; ++c) dst[c] = 0;
  } else if (idx < 10714523) {
    // zero v_frag tile-10 planes (tokens 320..351; proj refills 320..342)
    const int i = idx - 10517915;
    const int bh = i >> 7, c = i & 127;
    short8 z = (short8){0,0,0,0,0,0,0,0};
    *reinterpret_cast<short8*>(v_frag + bh * FPLANE + 10240 + c * 8) = z;
  }
}

// ---------------- kernel A: fused Q/K/V projection ----------------
__global__ __launch_bounds__(256) void proj(
    const unsigned short* __restrict__ x1b, const unsigned short* __restrict__ x2b,
    const unsigned short* __restrict__ wq_bf, const unsigned short* __restrict__ wkv_bf,
    const float* __restrict__ qb, const float* __restrict__ kvb,
    unsigned short* __restrict__ q_g, unsigned short* __restrict__ k_g,
    unsigned short* __restrict__ v_frag)
{
  const int tid = threadIdx.x;
  const int wv = tid >> 6, lane = tid & 63, lg = lane >> 4, lr = lane & 15;
  const int path = blockIdx.y;
  const int row0 = blockIdx.x * 128 + wv * 32;

  const unsigned short* X = (path == 0) ? x1b : x2b;
  const unsigned short* W = (path == 0) ? wq_bf : (path == 1 ? wkv_bf : wkv_bf + 36864);
  const float* Bv = (path == 0) ? qb : (path == 1 ? kvb : kvb + 192);

  f32x4 acc[2][12];
  #pragma unroll
  for (int i = 0; i < 2; ++i)
    #pragma unroll
    for (int j = 0; j < 12; ++j) acc[i][j] = (f32x4){0.f, 0.f, 0.f, 0.f};

  const unsigned short* xr0 = X + (row0 + lr) * 192;
  const unsigned short* xr1 = xr0 + 16 * 192;
  const unsigned short* wr  = W + lr * 192;

  if (path < 2) {
    #pragma unroll
    for (int kk = 0; kk < 6; ++kk) {
      const int k0 = kk * 32 + lg * 8;
      const short8 a0 = ld8(xr0 + k0);
      const short8 a1 = ld8(xr1 + k0);
      #pragma unroll
      for (int ct = 0; ct < 12; ++ct) {
        const short8 wf = ld8(wr + ct * 3072 + k0);
        acc[0][ct] = __builtin_amdgcn_mfma_f32_16x16x32_bf16(a0, wf, acc[0][ct], 0, 0, 0);
        acc[1][ct] = __builtin_amdgcn_mfma_f32_16x16x32_bf16(a1, wf, acc[1][ct], 0, 0, 0);
      }
    }
    const float scale = (path == 0) ? (0.17677669529663687f * LOG2E) : 1.0f;
    float bs[12];
    #pragma unroll
    for (int ct = 0; ct < 12; ++ct) bs[ct] = Bv[ct * 16 + lr];
    if (path == 0) {
      #pragma unroll
      for (int rs = 0; rs < 2; ++rs) {
        const int t0 = row0 + rs * 16 + lg * 4;
        const int b0 = t0 / NTOK;
        const int n0 = t0 - b0 * NTOK;
        #pragma unroll
        for (int r = 0; r < 4; ++r) {
          int b = b0, n = n0 + r;
          if (n >= NTOK) { b++; n -= NTOK; }
          unsigned short* ob = q_g + (b * 6 * NTOK + n) * 32 + lr;
          #pragma unroll
          for (int ct = 0; ct < 12; ++ct) {
            const int h = ct >> 1, dhi = (ct & 1) * 16;
            ob[h * (NTOK * 32) + dhi] = f2bf((acc[rs][ct][r] + bs[ct]) * scale);
          }
        }
      }
    } else {
      // K -> fragment-linear planes
      #pragma unroll
      for (int rs = 0; rs < 2; ++rs) {
        const int t0 = row0 + rs * 16 + lg * 4;
        const int b0 = t0 / NTOK;
        const int n0 = t0 - b0 * NTOK;
        #pragma unroll
        for (int r = 0; r < 4; ++r) {
          int b = b0, n = n0 + r;
          if (n >= NTOK) { b++; n -= NTOK; }
          const int kt = n >> 5, n31 = n & 31;
          unsigned short* ob = k_g + b * 6 * FPLANE + kt * 1024
                               + ((lr >> 3) * 32 + n31) * 8 + (lr & 7);
          #pragma unroll
          for (int ct = 0; ct < 12; ++ct) {
            const int h = ct >> 1;
            ob[h * FPLANE + (ct & 1) * 512] = f2bf(acc[rs][ct][r] + bs[ct]);
          }
        }
      }
    }
  } else {
    #pragma unroll
    for (int kk = 0; kk < 6; ++kk) {
      const int k0 = kk * 32 + lg * 8;
      const short8 a0 = ld8(xr0 + k0);
      const short8 a1 = ld8(xr1 + k0);
      #pragma unroll
      for (int ct = 0; ct < 12; ++ct) {
        const short8 wf = ld8(wr + ct * 3072 + k0);
        acc[0][ct] = __builtin_amdgcn_mfma_f32_16x16x32_bf16(wf, a0, acc[0][ct], 0, 0, 0);
        acc[1][ct] = __builtin_amdgcn_mfma_f32_16x16x32_bf16(wf, a1, acc[1][ct], 0, 0, 0);
      }
    }
    f32x4 bv[12];
    #pragma unroll
    for (int ct = 0; ct < 12; ++ct)
      bv[ct] = *reinterpret_cast<const f32x4*>(Bv + ct * 16 + lg * 4);
    // V -> fragment-linear planes (V^T: rows = d, cols = tok)
    #pragma unroll
    for (int tt = 0; tt < 2; ++tt) {
      const int t = row0 + tt * 16 + lr;
      const int b = t / NTOK;
      const int n = t - b * NTOK;
      const int kt = n >> 5;
      unsigned short* vb = v_frag + b * 6 * FPLANE + kt * 1024
                           + (((n >> 3) & 1) * 32) * 8 + ((n >> 4) & 1) * 512 + (n & 7);
      #pragma unroll
      for (int ct = 0; ct < 12; ++ct) {
        #pragma unroll
        for (int r = 0; r < 4; ++r) {
          const int c2 = ct * 16 + lg * 4 + r;
          const int h = c2 >> 5, d = c2 & 31;
          vb[h * FPLANE + d * 8] = f2bf(acc[tt][ct][r] + bv[ct][r]);
        }
      }
    }
  }
}

// ---------------- kernel C: attention v5 (LDS fragment K/V + reg softmax) ----------------
__global__ __launch_bounds__(256, 3) void attn(
    const unsigned short* __restrict__ q_g, const unsigned short* __restrict__ k_g,
    const unsigned short* __restrict__ v_frag, const unsigned short* __restrict__ bias_bf,
    const unsigned short* __restrict__ mask_bf, unsigned short* __restrict__ attn_out)
{
  __shared__ __align__(16) unsigned short kvlds[2][FPLANE];

  const int tid = threadIdx.x;
  const int wv = tid >> 6, lane = tid & 63;
  const int l31 = lane & 31, hi = lane >> 5;
  const int bid = blockIdx.x;
  const int b = bid / 6, h = bid - b * 6;
  const int w = b & 63;

  const unsigned short* qp = q_g + bid * (NTOK * 32);
  const unsigned short* kpf = k_g + bid * FPLANE;
  const unsigned short* vpf = v_frag + bid * FPLANE;
  const unsigned short* bias_h = bias_bf + h * (NTOK * BMP);
  const unsigned short* mask_w = mask_bf + w * (NTOK * BMP);

  // stage K and V planes (linear copy, coalesced, conflict-free)
  #pragma unroll
  for (int j = 0; j < 6; ++j) {
    const int c = j * 256 + tid;
    if (c < 1408) {
      *reinterpret_cast<short8*>(&kvlds[0][c * 8]) = ld8(kpf + c * 8);
      *reinterpret_cast<short8*>(&kvlds[1][c * 8]) = ld8(vpf + c * 8);
    }
  }
  __syncthreads();

  for (int qt = wv; qt < 11; qt += 4) {
    const int qq = qt * 32 + l31;
    const int qrc = qq < NTOK ? qq : NTOK - 1;
    const short8 qf0 = ld8(qp + qrc * 32 + hi * 8);
    const short8 qf1 = ld8(qp + qrc * 32 + 16 + hi * 8);
    const unsigned short* bmb = bias_h + qrc * BMP + hi * 4;
    const unsigned short* bmm = mask_w + qrc * BMP + hi * 4;

    f32x16 O;
    #pragma unroll
    for (int r = 0; r < 16; ++r) O[r] = 0.f;
    float m = -3.0e38f, sum = 0.f;

    // prefetch bias/mask for kt=0
    us4 nb[4], nm[4];
    #pragma unroll
    for (int g = 0; g < 4; ++g) {
      nb[g] = *reinterpret_cast<const us4*>(bmb + g * 8);
      nm[g] = *reinterpret_cast<const us4*>(bmm + g * 8);
    }

    #pragma unroll
    for (int kt = 0; kt < 11; ++kt) {
      us4 cb[4], cm[4];
      #pragma unroll
      for (int g = 0; g < 4; ++g) { cb[g] = nb[g]; cm[g] = nm[g]; }
      if (kt < 10) {
        const int kn = (kt + 1) * 32;
        #pragma unroll
        for (int g = 0; g < 4; ++g) {
          nb[g] = *reinterpret_cast<const us4*>(bmb + kn + g * 8);
          nm[g] = *reinterpret_cast<const us4*>(bmm + kn + g * 8);
        }
      }

      // S^T tile from LDS fragments
      const short8 kf0 = ld8(&kvlds[0][kt * 1024 + lane * 8]);
      const short8 kf1 = ld8(&kvlds[0][kt * 1024 + 512 + lane * 8]);
      f32x16 s;
      #pragma unroll
      for (int r = 0; r < 16; ++r) s[r] = 0.f;
      s = mfma32(kf0, qf0, s);
      s = mfma32(kf1, qf1, s);

      float p[16];
      float tmax = -3.0e38f;
      #pragma unroll
      for (int g = 0; g < 4; ++g) {
        #pragma unroll
        for (int j = 0; j < 4; ++j) {
          float v = s[g * 4 + j] + (bf2f(cb[g][j]) + bf2f(cm[g][j]));
          if (kt == 10 && (g * 8 + hi * 4 + j) >= 23) v = -3.0e38f;
          p[g * 4 + j] = v;
          tmax = fmaxf(tmax, v);
        }
      }
      tmax = fmaxf(tmax, __shfl_xor(tmax, 32));

      if (!__all(tmax <= m + 8.f)) {
        const float newm = fmaxf(m, tmax);
        const float sc = fexp2(m - newm);
        m = newm;
        sum *= sc;
        #pragma unroll
        for (int r = 0; r < 16; ++r) O[r] *= sc;
      }

      #pragma unroll
      for (int r = 0; r < 16; ++r) p[r] = fexp2(p[r] - m);
      #pragma unroll
      for (int r = 0; r < 16; ++r) sum += p[r];

      const unsigned c01 = cvtpk(p[0], p[1]),  c23 = cvtpk(p[2], p[3]);
      const unsigned c45 = cvtpk(p[4], p[5]),  c67 = cvtpk(p[6], p[7]);
      const unsigned d01 = cvtpk(p[8], p[9]),  d23 = cvtpk(p[10], p[11]);
      const unsigned d45 = cvtpk(p[12], p[13]), d67 = cvtpk(p[14], p[15]);
      const unsigned sc01 = __shfl_xor((int)c01, 32), sc23 = __shfl_xor((int)c23, 32);
      const unsigned sc45 = __shfl_xor((int)c45, 32), sc67 = __shfl_xor((int)c67, 32);
      const unsigned sd01 = __shfl_xor((int)d01, 32), sd23 = __shfl_xor((int)d23, 32);
      const unsigned sd45 = __shfl_xor((int)d45, 32), sd67 = __shfl_xor((int)d67, 32);
      frag_u P0, P1;
      P0.u[0] = hi ? sc45 : c01;  P0.u[1] = hi ? sc67 : c23;
      P0.u[2] = hi ? c45 : sc01;  P0.u[3] = hi ? c67 : sc23;
      P1.u[0] = hi ? sd45 : d01;  P1.u[1] = hi ? sd67 : d23;
      P1.u[2] = hi ? d45 : sd01;  P1.u[3] = hi ? d67 : sd23;

      const short8 vf0 = ld8(&kvlds[1][kt * 1024 + lane * 8]);
      const short8 vf1 = ld8(&kvlds[1][kt * 1024 + 512 + lane * 8]);
      O = mfma32(vf0, P0.s8, O);
      O = mfma32(vf1, P1.s8, O);
    }

    const float sumT = sum + __shfl_xor(sum, 32);
    const float inv = 1.0f / sumT;
    if (qq < NTOK) {
      unsigned short* op = attn_out + (b * NTOK + qq) * 192 + h * 32;
      #pragma unroll
      for (int g = 0; g < 4; ++g) {
        us4 ov;
        #pragma unroll
        for (int j = 0; j < 4; ++j) ov[j] = f2bf(O[g * 4 + j] * inv);
        *reinterpret_cast<us4*>(op + g * 8 + hi * 4) = ov;
      }
    }
  }
}

// ---------------- kernel D: output projection ----------------
__global__ __launch_bounds__(256) void proj_out(
    const unsigned short* __restrict__ a_in, const unsigned short* __restrict__ wp_bf,
    const float* __restrict__ pb, float* __restrict__ out)
{
  const int tid = threadIdx.x;
  const int wv = tid >> 6, lane = tid & 63, lg = lane >> 4, lr = lane & 15;
  const int row0 = blockIdx.x * 128 + wv * 32;

  f32x4 acc[2][12];
  #pragma unroll
  for (int i = 0; i < 2; ++i)
    #pragma unroll
    for (int j = 0; j < 12; ++j) acc[i][j] = (f32x4){0.f, 0.f, 0.f, 0.f};

  const unsigned short* xr0 = a_in + (row0 + lr) * 192;
  const unsigned short* xr1 = xr0 + 16 * 192;
  const unsigned short* wr  = wp_bf + lr * 192;

  #pragma unroll
  for (int kk = 0; kk < 6; ++kk) {
    const int k0 = kk * 32 + lg * 8;
    const short8 a0 = ld8(xr0 + k0);
    const short8 a1 = ld8(xr1 + k0);
    #pragma unroll
    for (int ct = 0; ct < 12; ++ct) {
      const short8 wf = ld8(wr + ct * 3072 + k0);
      acc[0][ct] = __builtin_amdgcn_mfma_f32_16x16x32_bf16(a0, wf, acc[0][ct], 0, 0, 0);
      acc[1][ct] = __builtin_amdgcn_mfma_f32_16x16x32_bf16(a1, wf, acc[1][ct], 0, 0, 0);
    }
  }

  float bs[12];
  #pragma unroll
  for (int ct = 0; ct < 12; ++ct) bs[ct] = pb[ct * 16 + lr];
  #pragma unroll
  for (int rs = 0; rs < 2; ++rs) {
    #pragma unroll
    for (int r = 0; r < 4; ++r) {
      const int t = row0 + rs * 16 + lg * 4 + r;
      float* op = out + t * 192 + lr;
      #pragma unroll
      for (int ct = 0; ct < 12; ++ct)
        op[ct * 16] = acc[rs][ct][r] + bs[ct];
    }
  }
}

extern "C" void kernel_launch(void* const* d_in, const int* in_sizes, int n_in,
                              void* d_out, int out_size, void* d_ws, size_t ws_size,
                              hipStream_t stream) {
  const float* x1    = (const float*)d_in[0];
  const float* x2    = (const float*)d_in[1];
  const float* mask  = (const float*)d_in[2];
  const float* table = (const float*)d_in[3];
  const float* qw    = (const float*)d_in[4];
  const float* qb    = (const float*)d_in[5];
  const float* kvw   = (const float*)d_in[6];
  const float* kvb   = (const float*)d_in[7];
  const float* pw    = (const float*)d_in[8];
  const float* pb    = (const float*)d_in[9];
  const int* rel_idx = (const int*)d_in[10];

  char* ws = (char*)d_ws;
  char* outc = (char*)d_out;
  unsigned short* q_g     = (unsigned short*)(ws + OFF_QG);
  unsigned short* k_g     = (unsigned short*)(ws + OFF_KG);
  unsigned short* v_frag  = (unsigned short*)(ws + OFF_VT);
  unsigned short* a_o     = (unsigned short*)(ws + OFF_AO);
  unsigned short* wq_bf   = (unsigned short*)(ws + OFF_WB);
  unsigned short* wkv_bf  = wq_bf + 36864;
  unsigned short* wp_bf   = wkv_bf + 73728;
  unsigned short* x1b     = a_o;                               // aliased (dead after proj)
  unsigned short* x2b     = (unsigned short*)outc;             // aliased (d_out written last)
  unsigned short* bias_bf = (unsigned short*)(outc + 33718272);
  unsigned short* mask_bf = (unsigned short*)(outc + 35167104);

  hipLaunchKernelGGL(precompute, dim3(41854), dim3(256), 0, stream,
                     x1, x2, mask, table, rel_idx, qw, kvw, pw,
                     x1b, x2b, wq_bf, wkv_bf, wp_bf, bias_bf, mask_bf, v_frag);
  hipLaunchKernelGGL(proj, dim3(686, 3), dim3(256), 0, stream,
                     x1b, x2b, wq_bf, wkv_bf, qb, kvb, q_g, k_g, v_frag);
  hipLaunchKernelGGL(attn, dim3(1536), dim3(256), 0, stream,
                     q_g, k_g, v_frag, bias_bf, mask_bf, a_o);
  hipLaunchKernelGGL(proj_out, dim3(686), dim3(256), 0, stream,
                     a_o, wp_bf, pb, (float*)d_out);
}

// Round 6
// 238.086 us; speedup vs baseline: 2.0224x; 1.4202x over previous
//
#include <hip/hip_runtime.h>

typedef __attribute__((ext_vector_type(8))) short short8;
typedef __attribute__((ext_vector_type(4))) float f32x4;
typedef __attribute__((ext_vector_type(16))) float f32x16;
typedef __attribute__((ext_vector_type(4))) unsigned short us4;
typedef __attribute__((ext_vector_type(2))) unsigned int u32x2;

#define NTOK 343
#define BMP 352      // bias/mask padded row pitch (elements)
#define LOG2E 1.4426950408889634f
#define FPLANE 11264 // shorts per (b,h) fragment plane: 11 tiles x 1024
#define WPITCH 200   // LDS W row pitch (shorts)

// ---- workspace layout (bytes) ----
#define OFF_QG   0u            // q: [bh][tok][32]            33,718,272
#define OFF_KG   33718272u     // k frag planes: 1536*11264*2 34,603,008
#define OFF_VT   68321280u     // v frag planes               34,603,008
#define OFF_AO   102924288u    // x1b during pre/proj; a_o    33,718,272
#define OFF_WB   136642560u    // bf16 weights
// bias_bf/mask_bf live in spare d_out space

__device__ __forceinline__ unsigned short f2bf(float f) {
  union { float f; unsigned u; } v; v.f = f;
  unsigned r = v.u + 0x7FFFu + ((v.u >> 16) & 1u);
  return (unsigned short)(r >> 16);
}

__device__ __forceinline__ float bf2f(unsigned short b) {
  union { unsigned u; float f; } v; v.u = ((unsigned)b) << 16;
  return v.f;
}

__device__ __forceinline__ short8 ld8(const unsigned short* p) {
  return *reinterpret_cast<const short8*>(p);
}

__device__ __forceinline__ float fexp2(float x) {
  float r; asm("v_exp_f32 %0, %1" : "=v"(r) : "v"(x)); return r;
}

__device__ __forceinline__ unsigned cvtpk(float a, float b) {
  unsigned r; asm("v_cvt_pk_bf16_f32 %0, %1, %2" : "=v"(r) : "v"(a), "v"(b)); return r;
}

__device__ __forceinline__ f32x16 mfma32(short8 a, short8 b, f32x16 c) {
  return __builtin_amdgcn_mfma_f32_32x32x16_bf16(a, b, c, 0, 0, 0);
}

__device__ __forceinline__ f32x4 mfma16(short8 a, short8 b, f32x4 c) {
  return __builtin_amdgcn_mfma_f32_16x16x32_bf16(a, b, c, 0, 0, 0);
}

union frag_u { unsigned u[4]; short8 s8; };

// ---------------- kernel B: precompute ----------------
__global__ __launch_bounds__(256) void precompute(
    const float* __restrict__ x1, const float* __restrict__ x2,
    const float* __restrict__ mask, const float* __restrict__ table,
    const int* __restrict__ rel_idx,
    const float* __restrict__ qw, const float* __restrict__ kvw, const float* __restrict__ pw,
    unsigned short* __restrict__ x1b, unsigned short* __restrict__ x2b,
    unsigned short* __restrict__ wq_bf, unsigned short* __restrict__ wkv_bf,
    unsigned short* __restrict__ wp_bf,
    unsigned short* __restrict__ bias_bf, unsigned short* __restrict__ mask_bf,
    unsigned short* __restrict__ v_frag)
{
  const int idx = blockIdx.x * 256 + threadIdx.x;
  if (idx < 8429568) {
    const float* src; unsigned short* dst; int i;
    if (idx < 4214784) { src = x1; dst = x1b; i = idx; }
    else               { src = x2; dst = x2b; i = idx - 4214784; }
    f32x4 v = *reinterpret_cast<const f32x4*>(src + i * 4);
    us4 o; o[0] = f2bf(v[0]); o[1] = f2bf(v[1]); o[2] = f2bf(v[2]); o[3] = f2bf(v[3]);
    *reinterpret_cast<us4*>(dst + i * 4) = o;
  } else if (idx < 8466432) {
    const int wi = idx - 8429568;
    const float* src; unsigned short* dst; int i;
    if (wi < 9216)       { src = qw;  dst = wq_bf;  i = wi; }
    else if (wi < 27648) { src = kvw; dst = wkv_bf; i = wi - 9216; }
    else                 { src = pw;  dst = wp_bf;  i = wi - 27648; }
    f32x4 v = *reinterpret_cast<const f32x4*>(src + i * 4);
    us4 o; o[0] = f2bf(v[0]); o[1] = f2bf(v[1]); o[2] = f2bf(v[2]); o[3] = f2bf(v[3]);
    *reinterpret_cast<us4*>(dst + i * 4) = o;
  } else if (idx < 10398208) {
    const int mi = idx - 8466432;
    const int row = mi / 88, q = mi - row * 88;
    const int j0 = q * 4;
    unsigned short* dst = mask_bf + row * BMP + j0;
    if (q < 85) {
      const float* src = mask + row * NTOK + j0;
      us4 o; o[0] = f2bf(LOG2E * src[0]); o[1] = f2bf(LOG2E * src[1]);
      o[2] = f2bf(LOG2E * src[2]); o[3] = f2bf(LOG2E * src[3]);
      *reinterpret_cast<us4*>(dst) = o;
    } else {
      us4 o;
      #pragma unroll
      for (int i = 0; i < 4; ++i) {
        const int col = j0 + i;
        o[i] = (col < NTOK) ? f2bf(LOG2E * mask[row * NTOK + col]) : (unsigned short)0;
      }
      *reinterpret_cast<us4*>(dst) = o;
    }
  } else if (idx < 10515857) {
    const int i = idx - 10398208;
    const int ri = rel_idx[i] * 6;
    const int rrow = i / NTOK, j = i - rrow * NTOK;
    unsigned short* dst = bias_bf + rrow * BMP + j;
    #pragma unroll
    for (int h = 0; h < 6; ++h) dst[h * (NTOK * BMP)] = f2bf(LOG2E * table[ri + h]);
  } else if (idx < 10517915) {
    const int p = idx - 10515857;
    unsigned short* dst = bias_bf + p * BMP + NTOK;
    #pragma unroll
    for (int c = 0; c < 9; ++c) dst[c] = 0;
  } else if (idx < 10714523) {
    // zero v_frag tile-10 planes (tokens 320..351; proj refills 320..351)
    const int i = idx - 10517915;
    const int bh = i >> 7, c = i & 127;
    short8 z = (short8){0,0,0,0,0,0,0,0};
    *reinterpret_cast<short8*>(v_frag + bh * FPLANE + 10240 + c * 8) = z;
  }
}

// ---------------- kernel A: fused Q/K/V projection (LDS-W, per-window tiles) ----------------
// grid (768, 3): x -> b = x&255, seg = x>>8; y = path (0:Q 1:K 2:V)
// wave handles 32 tokens n0 = seg*128 + wv*32 (tokens >= 343 are junk, gated on store)
__global__ __launch_bounds__(256) void proj(
    const unsigned short* __restrict__ x1b, const unsigned short* __restrict__ x2b,
    const unsigned short* __restrict__ wq_bf, const unsigned short* __restrict__ wkv_bf,
    const float* __restrict__ qb, const float* __restrict__ kvb,
    unsigned short* __restrict__ q_g, unsigned short* __restrict__ k_g,
    unsigned short* __restrict__ v_frag)
{
  __shared__ __align__(16) unsigned short wLds[192 * WPITCH];

  const int tid = threadIdx.x;
  const int wv = tid >> 6, lane = tid & 63, lg = lane >> 4, lr = lane & 15;
  const int path = blockIdx.y;
  const int b = blockIdx.x & 255, seg = blockIdx.x >> 8;
  const int n0 = seg * 128 + wv * 32;

  const unsigned short* X = (path == 0) ? x1b : x2b;
  const unsigned short* Wsrc = (path == 0) ? wq_bf : (path == 1 ? wkv_bf : wkv_bf + 36864);

  // stage W tile (192x192) into LDS, padded rows
  #pragma unroll
  for (int i = 0; i < 18; ++i) {
    const int c = i * 256 + tid;
    const int row = c / 24, c8 = c - row * 24;
    *reinterpret_cast<short8*>(&wLds[row * WPITCH + c8 * 8]) = ld8(Wsrc + row * 192 + c8 * 8);
  }
  __syncthreads();

  const int rowbase = b * NTOK;
  const int nA = n0 + lr, nB = n0 + 16 + lr;
  const unsigned short* xr0 = X + (rowbase + (nA < NTOK ? nA : NTOK - 1)) * 192 + lg * 8;
  const unsigned short* xr1 = X + (rowbase + (nB < NTOK ? nB : NTOK - 1)) * 192 + lg * 8;

  // hoist all X fragments (12 loads, deep pipeline)
  short8 ax[2][6];
  #pragma unroll
  for (int kk = 0; kk < 6; ++kk) {
    ax[0][kk] = ld8(xr0 + kk * 32);
    ax[1][kk] = ld8(xr1 + kk * 32);
  }

  f32x4 acc[2][12];
  #pragma unroll
  for (int i = 0; i < 2; ++i)
    #pragma unroll
    for (int j = 0; j < 12; ++j) acc[i][j] = (f32x4){0.f, 0.f, 0.f, 0.f};

  if (path < 2) {
    // swapped: C rows = output channel c, cols = token
    #pragma unroll
    for (int kk = 0; kk < 6; ++kk) {
      const int k0 = kk * 32 + lg * 8;
      #pragma unroll
      for (int ct = 0; ct < 12; ++ct) {
        const short8 wf = *reinterpret_cast<const short8*>(&wLds[(ct * 16 + lr) * WPITCH + k0]);
        acc[0][ct] = mfma16(wf, ax[0][kk], acc[0][ct]);
        acc[1][ct] = mfma16(wf, ax[1][kk], acc[1][ct]);
      }
    }
    if (path == 0) {
      const float qs = 0.17677669529663687f * LOG2E;
      #pragma unroll
      for (int tt = 0; tt < 2; ++tt) {
        const int n = n0 + tt * 16 + lr;
        if (n < NTOK) {
          unsigned short* ob = q_g + (b * 6 * NTOK + n) * 32 + (lg & 1) * 0;  // base
          #pragma unroll
          for (int ct = 0; ct < 12; ++ct) {
            const f32x4 bb = *reinterpret_cast<const f32x4*>(qb + ct * 16 + lg * 4);
            u32x2 pk;
            pk[0] = cvtpk((acc[tt][ct][0] + bb[0]) * qs, (acc[tt][ct][1] + bb[1]) * qs);
            pk[1] = cvtpk((acc[tt][ct][2] + bb[2]) * qs, (acc[tt][ct][3] + bb[3]) * qs);
            *reinterpret_cast<u32x2*>(ob + (ct >> 1) * (NTOK * 32) + (ct & 1) * 16 + lg * 4) = pk;
          }
        }
      }
    } else {
      #pragma unroll
      for (int tt = 0; tt < 2; ++tt) {
        const int n = n0 + tt * 16 + lr;
        if (n < 352) {
          unsigned short* ob = k_g + b * 6 * FPLANE + (n >> 5) * 1024
                               + ((lg >> 1) * 32 + (n & 31)) * 8 + (lg & 1) * 4;
          #pragma unroll
          for (int ct = 0; ct < 12; ++ct) {
            const f32x4 bb = *reinterpret_cast<const f32x4*>(kvb + ct * 16 + lg * 4);
            u32x2 pk;
            pk[0] = cvtpk(acc[tt][ct][0] + bb[0], acc[tt][ct][1] + bb[1]);
            pk[1] = cvtpk(acc[tt][ct][2] + bb[2], acc[tt][ct][3] + bb[3]);
            *reinterpret_cast<u32x2*>(ob + (ct >> 1) * FPLANE + (ct & 1) * 512) = pk;
          }
        }
      }
    }
  } else {
    // unswapped: C rows = token, cols = channel c2 (V)
    #pragma unroll
    for (int kk = 0; kk < 6; ++kk) {
      const int k0 = kk * 32 + lg * 8;
      #pragma unroll
      for (int ct = 0; ct < 12; ++ct) {
        const short8 wf = *reinterpret_cast<const short8*>(&wLds[(ct * 16 + lr) * WPITCH + k0]);
        acc[0][ct] = mfma16(ax[0][kk], wf, acc[0][ct]);
        acc[1][ct] = mfma16(ax[1][kk], wf, acc[1][ct]);
      }
    }
    float bs[12];
    #pragma unroll
    for (int ct = 0; ct < 12; ++ct) bs[ct] = kvb[192 + ct * 16 + lr];
    const int d2lo = lr;  // d = (ct&1)*16 + lr
    #pragma unroll
    for (int tt = 0; tt < 2; ++tt) {
      const int nb = n0 + tt * 16 + lg * 4;
      if (nb < 352) {
        unsigned short* vb = v_frag + b * 6 * FPLANE + (nb >> 5) * 1024
                             + ((nb >> 4) & 1) * 512 + ((nb >> 3) & 1) * 256 + (nb & 7);
        #pragma unroll
        for (int ct = 0; ct < 12; ++ct) {
          const int d = (ct & 1) * 16 + d2lo;
          u32x2 pk;
          pk[0] = cvtpk(acc[tt][ct][0] + bs[ct], acc[tt][ct][1] + bs[ct]);
          pk[1] = cvtpk(acc[tt][ct][2] + bs[ct], acc[tt][ct][3] + bs[ct]);
          *reinterpret_cast<u32x2*>(vb + (ct >> 1) * FPLANE + d * 8) = pk;
        }
      }
    }
  }
}

// ---------------- kernel C: attention (LDS fragment K/V + reg softmax) ----------------
__global__ __launch_bounds__(256, 3) void attn(
    const unsigned short* __restrict__ q_g, const unsigned short* __restrict__ k_g,
    const unsigned short* __restrict__ v_frag, const unsigned short* __restrict__ bias_bf,
    const unsigned short* __restrict__ mask_bf, unsigned short* __restrict__ attn_out)
{
  __shared__ __align__(16) unsigned short kvlds[2][FPLANE];

  const int tid = threadIdx.x;
  const int wv = tid >> 6, lane = tid & 63;
  const int l31 = lane & 31, hi = lane >> 5;
  const int bid = blockIdx.x;
  const int b = bid / 6, h = bid - b * 6;
  const int w = b & 63;

  const unsigned short* qp = q_g + bid * (NTOK * 32);
  const unsigned short* kpf = k_g + bid * FPLANE;
  const unsigned short* vpf = v_frag + bid * FPLANE;
  const unsigned short* bias_h = bias_bf + h * (NTOK * BMP);
  const unsigned short* mask_w = mask_bf + w * (NTOK * BMP);

  // stage K and V planes (linear copy, coalesced, conflict-free)
  #pragma unroll
  for (int j = 0; j < 6; ++j) {
    const int c = j * 256 + tid;
    if (c < 1408) {
      *reinterpret_cast<short8*>(&kvlds[0][c * 8]) = ld8(kpf + c * 8);
      *reinterpret_cast<short8*>(&kvlds[1][c * 8]) = ld8(vpf + c * 8);
    }
  }
  __syncthreads();

  for (int qt = wv; qt < 11; qt += 4) {
    const int qq = qt * 32 + l31;
    const int qrc = qq < NTOK ? qq : NTOK - 1;
    const short8 qf0 = ld8(qp + qrc * 32 + hi * 8);
    const short8 qf1 = ld8(qp + qrc * 32 + 16 + hi * 8);
    const unsigned short* bmb = bias_h + qrc * BMP + hi * 4;
    const unsigned short* bmm = mask_w + qrc * BMP + hi * 4;

    f32x16 O;
    #pragma unroll
    for (int r = 0; r < 16; ++r) O[r] = 0.f;
    float m = -3.0e38f, sum = 0.f;

    // prefetch bias/mask for kt=0
    us4 nb[4], nm[4];
    #pragma unroll
    for (int g = 0; g < 4; ++g) {
      nb[g] = *reinterpret_cast<const us4*>(bmb + g * 8);
      nm[g] = *reinterpret_cast<const us4*>(bmm + g * 8);
    }

    #pragma unroll
    for (int kt = 0; kt < 11; ++kt) {
      us4 cb[4], cm[4];
      #pragma unroll
      for (int g = 0; g < 4; ++g) { cb[g] = nb[g]; cm[g] = nm[g]; }
      if (kt < 10) {
        const int kn = (kt + 1) * 32;
        #pragma unroll
        for (int g = 0; g < 4; ++g) {
          nb[g] = *reinterpret_cast<const us4*>(bmb + kn + g * 8);
          nm[g] = *reinterpret_cast<const us4*>(bmm + kn + g * 8);
        }
      }

      // S^T tile from LDS fragments
      const short8 kf0 = ld8(&kvlds[0][kt * 1024 + lane * 8]);
      const short8 kf1 = ld8(&kvlds[0][kt * 1024 + 512 + lane * 8]);
      f32x16 s;
      #pragma unroll
      for (int r = 0; r < 16; ++r) s[r] = 0.f;
      s = mfma32(kf0, qf0, s);
      s = mfma32(kf1, qf1, s);

      float p[16];
      float tmax = -3.0e38f;
      #pragma unroll
      for (int g = 0; g < 4; ++g) {
        #pragma unroll
        for (int j = 0; j < 4; ++j) {
          float v = s[g * 4 + j] + (bf2f(cb[g][j]) + bf2f(cm[g][j]));
          if (kt == 10 && (g * 8 + hi * 4 + j) >= 23) v = -3.0e38f;
          p[g * 4 + j] = v;
          tmax = fmaxf(tmax, v);
        }
      }
      tmax = fmaxf(tmax, __shfl_xor(tmax, 32));

      if (!__all(tmax <= m + 8.f)) {
        const float newm = fmaxf(m, tmax);
        const float sc = fexp2(m - newm);
        m = newm;
        sum *= sc;
        #pragma unroll
        for (int r = 0; r < 16; ++r) O[r] *= sc;
      }

      #pragma unroll
      for (int r = 0; r < 16; ++r) p[r] = fexp2(p[r] - m);
      #pragma unroll
      for (int r = 0; r < 16; ++r) sum += p[r];

      const unsigned c01 = cvtpk(p[0], p[1]),  c23 = cvtpk(p[2], p[3]);
      const unsigned c45 = cvtpk(p[4], p[5]),  c67 = cvtpk(p[6], p[7]);
      const unsigned d01 = cvtpk(p[8], p[9]),  d23 = cvtpk(p[10], p[11]);
      const unsigned d45 = cvtpk(p[12], p[13]), d67 = cvtpk(p[14], p[15]);
      const unsigned sc01 = __shfl_xor((int)c01, 32), sc23 = __shfl_xor((int)c23, 32);
      const unsigned sc45 = __shfl_xor((int)c45, 32), sc67 = __shfl_xor((int)c67, 32);
      const unsigned sd01 = __shfl_xor((int)d01, 32), sd23 = __shfl_xor((int)d23, 32);
      const unsigned sd45 = __shfl_xor((int)d45, 32), sd67 = __shfl_xor((int)d67, 32);
      frag_u P0, P1;
      P0.u[0] = hi ? sc45 : c01;  P0.u[1] = hi ? sc67 : c23;
      P0.u[2] = hi ? c45 : sc01;  P0.u[3] = hi ? c67 : sc23;
      P1.u[0] = hi ? sd45 : d01;  P1.u[1] = hi ? sd67 : d23;
      P1.u[2] = hi ? d45 : sd01;  P1.u[3] = hi ? d67 : sd23;

      const short8 vf0 = ld8(&kvlds[1][kt * 1024 + lane * 8]);
      const short8 vf1 = ld8(&kvlds[1][kt * 1024 + 512 + lane * 8]);
      O = mfma32(vf0, P0.s8, O);
      O = mfma32(vf1, P1.s8, O);
    }

    const float sumT = sum + __shfl_xor(sum, 32);
    const float inv = 1.0f / sumT;
    if (qq < NTOK) {
      unsigned short* op = attn_out + (b * NTOK + qq) * 192 + h * 32;
      #pragma unroll
      for (int g = 0; g < 4; ++g) {
        us4 ov;
        #pragma unroll
        for (int j = 0; j < 4; ++j) ov[j] = f2bf(O[g * 4 + j] * inv);
        *reinterpret_cast<us4*>(op + g * 8 + hi * 4) = ov;
      }
    }
  }
}

// ---------------- kernel D: output projection (LDS-W, swapped, f32x4 stores) ----------------
__global__ __launch_bounds__(256) void proj_out(
    const unsigned short* __restrict__ a_in, const unsigned short* __restrict__ wp_bf,
    const float* __restrict__ pb, float* __restrict__ out)
{
  __shared__ __align__(16) unsigned short wLds[192 * WPITCH];

  const int tid = threadIdx.x;
  const int wv = tid >> 6, lane = tid & 63, lg = lane >> 4, lr = lane & 15;
  const int t0 = blockIdx.x * 128 + wv * 32;

  #pragma unroll
  for (int i = 0; i < 18; ++i) {
    const int c = i * 256 + tid;
    const int row = c / 24, c8 = c - row * 24;
    *reinterpret_cast<short8*>(&wLds[row * WPITCH + c8 * 8]) = ld8(wp_bf + row * 192 + c8 * 8);
  }
  __syncthreads();

  const unsigned short* xr0 = a_in + (t0 + lr) * 192 + lg * 8;
  const unsigned short* xr1 = xr0 + 16 * 192;

  short8 ax[2][6];
  #pragma unroll
  for (int kk = 0; kk < 6; ++kk) {
    ax[0][kk] = ld8(xr0 + kk * 32);
    ax[1][kk] = ld8(xr1 + kk * 32);
  }

  f32x4 acc[2][12];
  #pragma unroll
  for (int i = 0; i < 2; ++i)
    #pragma unroll
    for (int j = 0; j < 12; ++j) acc[i][j] = (f32x4){0.f, 0.f, 0.f, 0.f};

  #pragma unroll
  for (int kk = 0; kk < 6; ++kk) {
    const int k0 = kk * 32 + lg * 8;
    #pragma unroll
    for (int ct = 0; ct < 12; ++ct) {
      const short8 wf = *reinterpret_cast<const short8*>(&wLds[(ct * 16 + lr) * WPITCH + k0]);
      acc[0][ct] = mfma16(wf, ax[0][kk], acc[0][ct]);
      acc[1][ct] = mfma16(wf, ax[1][kk], acc[1][ct]);
    }
  }

  #pragma unroll
  for (int tt = 0; tt < 2; ++tt) {
    const int t = t0 + tt * 16 + lr;
    float* op = out + t * 192 + lg * 4;
    #pragma unroll
    for (int ct = 0; ct < 12; ++ct) {
      const f32x4 bb = *reinterpret_cast<const f32x4*>(pb + ct * 16 + lg * 4);
      f32x4 ov;
      #pragma unroll
      for (int r = 0; r < 4; ++r) ov[r] = acc[tt][ct][r] + bb[r];
      *reinterpret_cast<f32x4*>(op + ct * 16) = ov;
    }
  }
}

extern "C" void kernel_launch(void* const* d_in, const int* in_sizes, int n_in,
                              void* d_out, int out_size, void* d_ws, size_t ws_size,
                              hipStream_t stream) {
  const float* x1    = (const float*)d_in[0];
  const float* x2    = (const float*)d_in[1];
  const float* mask  = (const float*)d_in[2];
  const float* table = (const float*)d_in[3];
  const float* qw    = (const float*)d_in[4];
  const float* qb    = (const float*)d_in[5];
  const float* kvw   = (const float*)d_in[6];
  const float* kvb   = (const float*)d_in[7];
  const float* pw    = (const float*)d_in[8];
  const float* pb    = (const float*)d_in[9];
  const int* rel_idx = (const int*)d_in[10];

  char* ws = (char*)d_ws;
  char* outc = (char*)d_out;
  unsigned short* q_g     = (unsigned short*)(ws + OFF_QG);
  unsigned short* k_g     = (unsigned short*)(ws + OFF_KG);
  unsigned short* v_frag  = (unsigned short*)(ws + OFF_VT);
  unsigned short* a_o     = (unsigned short*)(ws + OFF_AO);
  unsigned short* wq_bf   = (unsigned short*)(ws + OFF_WB);
  unsigned short* wkv_bf  = wq_bf + 36864;
  unsigned short* wp_bf   = wkv_bf + 73728;
  unsigned short* x1b     = a_o;                               // aliased (dead after proj)
  unsigned short* x2b     = (unsigned short*)outc;             // aliased (d_out written last)
  unsigned short* bias_bf = (unsigned short*)(outc + 33718272);
  unsigned short* mask_bf = (unsigned short*)(outc + 35167104);

  hipLaunchKernelGGL(precompute, dim3(41854), dim3(256), 0, stream,
                     x1, x2, mask, table, rel_idx, qw, kvw, pw,
                     x1b, x2b, wq_bf, wkv_bf, wp_bf, bias_bf, mask_bf, v_frag);
  hipLaunchKernelGGL(proj, dim3(768, 3), dim3(256), 0, stream,
                     x1b, x2b, wq_bf, wkv_bf, qb, kvb, q_g, k_g, v_frag);
  hipLaunchKernelGGL(attn, dim3(1536), dim3(256), 0, stream,
                     q_g, k_g, v_frag, bias_bf, mask_bf, a_o);
  hipLaunchKernelGGL(proj_out, dim3(686), dim3(256), 0, stream,
                     a_o, wp_bf, pb, (float*)d_out);
}